// Round 8
// baseline (79.659 us; speedup 1.0000x reference)
//
#include <hip/hip_runtime.h>
#include <math.h>

#define BB   8
#define IND  128
#define OUTD 128
#define NN   256
#define NQ   64          // NN/4 float4 quads
#define BN_EPS 1e-5f
#define ZW   4           // waves per block, each owns IND/ZW = 32 i-rows
#define ISL  (IND/ZW)
#define PST  25          // LDS partial stride: 24 values + 1; 25 coprime 32 -> 2-way (free)

// ---------------- Kernel 1: projections + Y + ReLU + BN partials ------------
// Grid (64 channel-pairs, 8 b) = 512 blocks, block (64, ZW=4) = 4 waves.
// Each block computes TWO channels from one read of the A[b] slab:
//   total A traffic 128 MB -> 64 MB; per-CU 512 KB -> 256 KB.
//   (R4/R7 showed the projection phase is per-CU-load-BW-bound at ~14-20 B/cyc,
//    invariant to TLP -> bytes/CU is the cost function.)
// z-waves cover i-quarters; partials combine via stride-25 LDS (conflict-free).
__global__ __launch_bounds__(64 * ZW) void k1_proj(
    const float* __restrict__ A,    // [B, IND, NN]
    const float* __restrict__ P1,   // [OUTD, IND]
    const float* __restrict__ P2,   // [OUTD, IND]
    const float* __restrict__ kw,   // [OUTD, IND]
    float* __restrict__ pbuf,       // ws: [B, OUTD, NN] post-ReLU pre-BN
    float* __restrict__ bnp)        // ws: [2][OUTD][BB] {sum, sumsq}
{
    const int cg = blockIdx.x;      // channel pair 0..63
    const int b  = blockIdx.y;
    const int x  = threadIdx.x;     // lane 0..63 = n-quad
    const int z  = threadIdx.y;     // i-quarter 0..3
    const int c0 = cg * 2;
    const int c1 = c0 + 1;

    const float4* __restrict__ A4 = (const float4*)A + (size_t)b * IND * NQ;
    const float* __restrict__ w1a = P1 + c0 * IND;
    const float* __restrict__ w1b = P1 + c1 * IND;
    const float* __restrict__ w2a = P2 + c0 * IND;
    const float* __restrict__ w2b = P2 + c1 * IND;
    const float* __restrict__ w3a = kw + c0 * IND;
    const float* __restrict__ w3b = kw + c1 * IND;

    float a1[2][4] = {{0.f,0.f,0.f,0.f},{0.f,0.f,0.f,0.f}};
    float vv[2][4] = {{0.f,0.f,0.f,0.f},{0.f,0.f,0.f,0.f}};
    float kv[2][4] = {{0.f,0.f,0.f,0.f},{0.f,0.f,0.f,0.f}};

    const int ibase = z * ISL;
    #pragma unroll
    for (int blk = 0; blk < ISL / 8; ++blk) {
        float4 cur[8];
        #pragma unroll
        for (int j = 0; j < 8; ++j)
            cur[j] = A4[(ibase + blk * 8 + j) * NQ + x];   // 8 loads in flight
        #pragma unroll
        for (int j = 0; j < 8; ++j) {
            const int i = ibase + blk * 8 + j;
            const float wa0 = w1a[i], wa1 = w1b[i];        // uniform -> SGPR
            const float wb0 = w2a[i], wb1 = w2b[i];
            const float wc0 = w3a[i], wc1 = w3b[i];
            a1[0][0]=fmaf(wa0,cur[j].x,a1[0][0]); a1[0][1]=fmaf(wa0,cur[j].y,a1[0][1]);
            a1[0][2]=fmaf(wa0,cur[j].z,a1[0][2]); a1[0][3]=fmaf(wa0,cur[j].w,a1[0][3]);
            a1[1][0]=fmaf(wa1,cur[j].x,a1[1][0]); a1[1][1]=fmaf(wa1,cur[j].y,a1[1][1]);
            a1[1][2]=fmaf(wa1,cur[j].z,a1[1][2]); a1[1][3]=fmaf(wa1,cur[j].w,a1[1][3]);
            vv[0][0]=fmaf(wb0,cur[j].x,vv[0][0]); vv[0][1]=fmaf(wb0,cur[j].y,vv[0][1]);
            vv[0][2]=fmaf(wb0,cur[j].z,vv[0][2]); vv[0][3]=fmaf(wb0,cur[j].w,vv[0][3]);
            vv[1][0]=fmaf(wb1,cur[j].x,vv[1][0]); vv[1][1]=fmaf(wb1,cur[j].y,vv[1][1]);
            vv[1][2]=fmaf(wb1,cur[j].z,vv[1][2]); vv[1][3]=fmaf(wb1,cur[j].w,vv[1][3]);
            kv[0][0]=fmaf(wc0,cur[j].x,kv[0][0]); kv[0][1]=fmaf(wc0,cur[j].y,kv[0][1]);
            kv[0][2]=fmaf(wc0,cur[j].z,kv[0][2]); kv[0][3]=fmaf(wc0,cur[j].w,kv[0][3]);
            kv[1][0]=fmaf(wc1,cur[j].x,kv[1][0]); kv[1][1]=fmaf(wc1,cur[j].y,kv[1][1]);
            kv[1][2]=fmaf(wc1,cur[j].z,kv[1][2]); kv[1][3]=fmaf(wc1,cur[j].w,kv[1][3]);
        }
    }

    // z>0 -> z=0 handoff: 24 partials/lane, stride 25 (coprime 32, conflict-free).
    __shared__ float part[ZW - 1][64][PST];
    if (z > 0) {
        float* dst = part[z - 1][x];
        #pragma unroll
        for (int ch = 0; ch < 2; ++ch)
            #pragma unroll
            for (int j = 0; j < 4; ++j) {
                dst[ch * 12 + j]     = a1[ch][j];
                dst[ch * 12 + 4 + j] = vv[ch][j];
                dst[ch * 12 + 8 + j] = kv[ch][j];
            }
    }
    __syncthreads();
    if (z != 0) return;

    #pragma unroll
    for (int zz = 0; zz < ZW - 1; ++zz) {
        const float* src = part[zz][x];
        #pragma unroll
        for (int ch = 0; ch < 2; ++ch)
            #pragma unroll
            for (int j = 0; j < 4; ++j) {
                a1[ch][j] += src[ch * 12 + j];
                vv[ch][j] += src[ch * 12 + 4 + j];
                kv[ch][j] += src[ch * 12 + 8 + j];
            }
    }

    // Per-channel S2 = sum_n kv^2, SV = sum_n |kv|*vv (n fully in-wave).
    float s2[2], sv[2];
    #pragma unroll
    for (int ch = 0; ch < 2; ++ch) {
        s2[ch] = 0.f; sv[ch] = 0.f;
        #pragma unroll
        for (int j = 0; j < 4; ++j) {
            s2[ch] = fmaf(kv[ch][j], kv[ch][j], s2[ch]);
            sv[ch] = fmaf(fabsf(kv[ch][j]), vv[ch][j], sv[ch]);
        }
    }
    #pragma unroll
    for (int off = 32; off >= 1; off >>= 1) {
        s2[0] += __shfl_xor(s2[0], off, 64);
        sv[0] += __shfl_xor(sv[0], off, 64);
        s2[1] += __shfl_xor(s2[1], off, 64);
        sv[1] += __shfl_xor(sv[1], off, 64);
    }

    float p[2][4];
    float bnsum[2], bnsq[2];
    #pragma unroll
    for (int ch = 0; ch < 2; ++ch) {
        const float y = sv[ch] / sqrtf(s2[ch]);  // Y rank-0 per (b,c); Q cancels.
        bnsum[ch] = 0.f; bnsq[ch] = 0.f;
        #pragma unroll
        for (int j = 0; j < 4; ++j) {
            float t = a1[ch][j] + vv[ch][j] + 0.1f * y;
            t = fmaxf(t, 0.f);                   // ReLU
            p[ch][j] = t;
            bnsum[ch] += t;
            bnsq[ch]  = fmaf(t, t, bnsq[ch]);
        }
    }
    #pragma unroll
    for (int off = 32; off >= 1; off >>= 1) {
        bnsum[0] += __shfl_xor(bnsum[0], off, 64);
        bnsq[0]  += __shfl_xor(bnsq[0],  off, 64);
        bnsum[1] += __shfl_xor(bnsum[1], off, 64);
        bnsq[1]  += __shfl_xor(bnsq[1],  off, 64);
    }

    float4* __restrict__ p4 = (float4*)pbuf;
    p4[((size_t)b * OUTD + c0) * NQ + x] = make_float4(p[0][0], p[0][1], p[0][2], p[0][3]);
    p4[((size_t)b * OUTD + c1) * NQ + x] = make_float4(p[1][0], p[1][1], p[1][2], p[1][3]);
    if (x == 0) {
        bnp[c0 * BB + b]             = bnsum[0];
        bnp[c1 * BB + b]             = bnsum[1];
        bnp[OUTD * BB + c0 * BB + b] = bnsq[0];
        bnp[OUTD * BB + c1 * BB + b] = bnsq[1];
    }
}

// ---------------- Kernel 2: BatchNorm combine + affine + store -------------
// Grid (128 c, 8 b) x 64 threads = 1024 blocks over all 256 CUs.
__global__ __launch_bounds__(64) void k2_bn(
    const float* __restrict__ pbuf,  // [B, OUTD, NN]
    const float* __restrict__ bnp,   // [2][OUTD][BB]
    const float* __restrict__ gamma,
    const float* __restrict__ beta,
    float* __restrict__ out)         // [B, OUTD, NN]
{
    const int c = blockIdx.x;
    const int b = blockIdx.y;
    const int x = threadIdx.x;

    float tsum = 0.f, tsq = 0.f;
    #pragma unroll
    for (int w = 0; w < BB; ++w) {   // uniform addresses -> scalar loads (L2 hit)
        tsum += bnp[c * BB + w];
        tsq  += bnp[OUTD * BB + c * BB + w];
    }
    const float inv   = 1.f / (float)(BB * NN);
    const float mean  = tsum * inv;
    const float var   = tsq * inv - mean * mean;     // biased var = jnp.var
    const float scale = gamma[c] * rsqrtf(var + BN_EPS);
    const float shift = beta[c] - mean * scale;

    const float4* __restrict__ p4 = (const float4*)pbuf;
    float4* __restrict__ out4 = (float4*)out;
    const size_t idx = ((size_t)b * OUTD + c) * NQ + x;
    const float4 p = p4[idx];
    out4[idx] = make_float4(fmaf(p.x, scale, shift), fmaf(p.y, scale, shift),
                            fmaf(p.z, scale, shift), fmaf(p.w, scale, shift));
}

extern "C" void kernel_launch(void* const* d_in, const int* in_sizes, int n_in,
                              void* d_out, int out_size, void* d_ws, size_t ws_size,
                              hipStream_t stream) {
    // setup_inputs order: A, P1, P2, q, k, gamma, beta, permutation_size1, BATCH_SIZE
    const float* A     = (const float*)d_in[0];
    const float* P1    = (const float*)d_in[1];
    const float* P2    = (const float*)d_in[2];
    // d_in[3] = q : unused (cancels in Alpha_norm)
    const float* kw    = (const float*)d_in[4];
    const float* gamma = (const float*)d_in[5];
    const float* beta  = (const float*)d_in[6];
    float* out = (float*)d_out;

    float* pbuf = (float*)d_ws;                                  // 1 MB
    float* bnp  = (float*)((char*)d_ws + (size_t)BB * OUTD * NN * sizeof(float));

    k1_proj<<<dim3(OUTD / 2, BB), dim3(64, ZW), 0, stream>>>(A, P1, P2, kw, pbuf, bnp);
    k2_bn<<<dim3(OUTD, BB), 64, 0, stream>>>(pbuf, bnp, gamma, beta, out);
}

// Round 9
// 77.894 us; speedup vs baseline: 1.0227x; 1.0227x over previous
//
#include <hip/hip_runtime.h>
#include <math.h>

#define BB   8
#define IND  128
#define OUTD 128
#define NN   256
#define NQ   64          // NN/4 float4 quads
#define BN_EPS 1e-5f

// Single dispatch, minimal-sync floor probe.
// Grid = 128 blocks (one per channel c). Block (64, 8): threadIdx.y = batch b
// = wave id -> S2/SV reductions are pure wave-64 butterflies (no LDS).
// Explicit 8-deep float4 load batches force ~32 load-result VGPRs in flight
// (R2's register-minimized schedule had ~2 -> 46 us; R3 fixed it but paid
// 16 waves + 2 barriers + LDS round-trip). One __syncthreads total, for the
// 8-entry BN combine; out stored directly from registers.
__global__ __launch_bounds__(512) void layer1dpe_one(
    const float* __restrict__ A,    // [B, IND, NN]
    const float* __restrict__ P1,   // [OUTD, IND]
    const float* __restrict__ P2,   // [OUTD, IND]
    const float* __restrict__ kw,   // [OUTD, IND]
    const float* __restrict__ gamma,// [OUTD]
    const float* __restrict__ beta, // [OUTD]
    float* __restrict__ out)        // [B, OUTD, NN]
{
    const int c = blockIdx.x;
    const int x = threadIdx.x;      // lane 0..63 = n-quad
    const int b = threadIdx.y;      // batch = wave id 0..7

    const float4* __restrict__ A4 = (const float4*)A + (size_t)b * IND * NQ;
    const float* __restrict__ w1 = P1 + c * IND;   // uniform -> scalar path
    const float* __restrict__ w2 = P2 + c * IND;
    const float* __restrict__ w3 = kw + c * IND;

    float a1[4] = {0.f, 0.f, 0.f, 0.f};
    float vv[4] = {0.f, 0.f, 0.f, 0.f};
    float kv[4] = {0.f, 0.f, 0.f, 0.f};

    #pragma unroll
    for (int blk = 0; blk < 16; ++blk) {
        float4 cur[8];
        #pragma unroll
        for (int j = 0; j < 8; ++j)
            cur[j] = A4[(blk * 8 + j) * NQ + x];     // 8 loads in flight
        #pragma unroll
        for (int j = 0; j < 8; ++j) {
            const int i = blk * 8 + j;
            const float wa = w1[i], wb = w2[i], wc = w3[i];
            a1[0] = fmaf(wa, cur[j].x, a1[0]); a1[1] = fmaf(wa, cur[j].y, a1[1]);
            a1[2] = fmaf(wa, cur[j].z, a1[2]); a1[3] = fmaf(wa, cur[j].w, a1[3]);
            vv[0] = fmaf(wb, cur[j].x, vv[0]); vv[1] = fmaf(wb, cur[j].y, vv[1]);
            vv[2] = fmaf(wb, cur[j].z, vv[2]); vv[3] = fmaf(wb, cur[j].w, vv[3]);
            kv[0] = fmaf(wc, cur[j].x, kv[0]); kv[1] = fmaf(wc, cur[j].y, kv[1]);
            kv[2] = fmaf(wc, cur[j].z, kv[2]); kv[3] = fmaf(wc, cur[j].w, kv[3]);
        }
    }

    // S2 = sum_n kv^2, SV = sum_n |kv|*vv : batch==wave -> pure butterfly.
    float s2 = 0.f, sv = 0.f;
    #pragma unroll
    for (int j = 0; j < 4; ++j) {
        s2 = fmaf(kv[j], kv[j], s2);
        sv = fmaf(fabsf(kv[j]), vv[j], sv);
    }
    #pragma unroll
    for (int off = 32; off >= 1; off >>= 1) {
        s2 += __shfl_xor(s2, off, 64);
        sv += __shfl_xor(sv, off, 64);
    }
    const float y = sv / sqrtf(s2);   // Y[b,c,i] == SV/||K||, i-free; Q cancels.

    float p[4];
    float bnsum = 0.f, bnsq = 0.f;
    #pragma unroll
    for (int j = 0; j < 4; ++j) {
        float t = a1[j] + vv[j] + 0.1f * y;
        t = fmaxf(t, 0.f);            // ReLU
        p[j] = t;
        bnsum += t;
        bnsq  = fmaf(t, t, bnsq);
    }
    #pragma unroll
    for (int off = 32; off >= 1; off >>= 1) {
        bnsum += __shfl_xor(bnsum, off, 64);
        bnsq  += __shfl_xor(bnsq,  off, 64);
    }

    // Block-local BN combine over the 8 batch-waves (the only barrier).
    __shared__ float red[BB][2];
    if (x == 0) { red[b][0] = bnsum; red[b][1] = bnsq; }
    __syncthreads();
    float tsum = 0.f, tsq = 0.f;
    #pragma unroll
    for (int w = 0; w < BB; ++w) { tsum += red[w][0]; tsq += red[w][1]; }

    const float inv   = 1.f / (float)(BB * NN);
    const float mean  = tsum * inv;
    const float var   = tsq * inv - mean * mean;     // biased var = jnp.var
    const float scale = gamma[c] * rsqrtf(var + BN_EPS);
    const float shift = beta[c] - mean * scale;

    float4* __restrict__ out4 = (float4*)out;
    out4[((size_t)b * OUTD + c) * NQ + x] = make_float4(
        fmaf(p[0], scale, shift), fmaf(p[1], scale, shift),
        fmaf(p[2], scale, shift), fmaf(p[3], scale, shift));
}

extern "C" void kernel_launch(void* const* d_in, const int* in_sizes, int n_in,
                              void* d_out, int out_size, void* d_ws, size_t ws_size,
                              hipStream_t stream) {
    // setup_inputs order: A, P1, P2, q, k, gamma, beta, permutation_size1, BATCH_SIZE
    const float* A     = (const float*)d_in[0];
    const float* P1    = (const float*)d_in[1];
    const float* P2    = (const float*)d_in[2];
    // d_in[3] = q : unused (cancels in Alpha_norm)
    const float* kw    = (const float*)d_in[4];
    const float* gamma = (const float*)d_in[5];
    const float* beta  = (const float*)d_in[6];
    float* out = (float*)d_out;

    layer1dpe_one<<<OUTD, dim3(64, BB), 0, stream>>>(A, P1, P2, kw, gamma, beta, out);
}